// Round 5
// baseline (217.788 us; speedup 1.0000x reference)
//
#include <hip/hip_runtime.h>

#define B_    16
#define L_    2048
#define S_    1024
#define DE_   512
#define D_    256
#define NSIL_ 8
#define A_    64
#define MS_   (B_ * S_)   // 16384 sentence rows

// GEMM tile: 128x64, BK=64, 4 waves (2x2), per-wave 64x32 via 16x16x32 MFMA
#define BM 128
#define BN 64
#define BK 64
#define NGEMM 512          // gemm blocks: (MS_/BM)*(D_/BN)
#define NT01  256          // t{0,1}-select blocks, 128 rows each

typedef __attribute__((ext_vector_type(8))) short  short8;
typedef __attribute__((ext_vector_type(4))) float  f32x4;

__device__ __forceinline__ unsigned short f2bf(float f) {
    unsigned int x = __builtin_bit_cast(unsigned int, f);
    x += 0x7fffu + ((x >> 16) & 1u);
    return (unsigned short)(x >> 16);
}
__device__ __forceinline__ float bf2f(unsigned short u) {
    unsigned int x = ((unsigned int)u) << 16;
    return __builtin_bit_cast(float, x);
}

// ---------------------------------------------------------------------------
// wT[n][k] = bf16(w[k][n])   (256 x 512 bf16 = 256 KB, one-time)
// ---------------------------------------------------------------------------
__global__ __launch_bounds__(256) void srse_wt(
    const float* __restrict__ w, unsigned short* __restrict__ wT)
{
    const int k = blockIdx.x;        // 0..511
    const int n = threadIdx.x;       // 0..255
    wT[n * DE_ + k] = f2bf(w[k * D_ + n]);
}

// ---------------------------------------------------------------------------
// Fused: blocks [0,NGEMM) = bf16 MFMA GEMM  Pb = bf16(sent @ w + b);
//        blocks [NGEMM, NGEMM+NT01) = t==0/1 output rows (independent of P,
//        latency hides under concurrent GEMM blocks).
// ---------------------------------------------------------------------------
__global__ __launch_bounds__(256) void srse_gemm_t01(
    const float*          __restrict__ sent,      // (MS_, DE_) f32
    const unsigned short* __restrict__ wT,        // (D_, DE_)  bf16
    const float*          __restrict__ bsh,       // (D_)
    unsigned short*       __restrict__ Pb,        // (MS_, D_)  bf16 out
    const float*          __restrict__ op_emb,    // (VOP, D_)
    const float*          __restrict__ silent,    // (NSIL_, D_)
    const float*          __restrict__ nodes,     // (NN, D_)
    const int*            __restrict__ op_tokens, // (B*L)
    const int*            __restrict__ arg_idx,   // (B*L)
    const int*            __restrict__ item_type, // (B*L)
    const int*            __restrict__ avail,     // (B*L, A_)
    float*                __restrict__ out)       // (B*L, D_)
{
    __shared__ alignas(16) unsigned short As[BM * BK]; // [row][k] swizzled
    __shared__ alignas(16) unsigned short Bs[BN * BK]; // [n][k]   swizzled

    const int t    = threadIdx.x;
    const int lane = t & 63;
    const int wid  = t >> 6;

    if (blockIdx.x < NGEMM) {
        // ---------------- GEMM path ----------------
        // XCD-chunked swizzle (512 % 8 == 0 -> bijective simple form)
        const int wg  = (blockIdx.x & 7) * (NGEMM / 8) + (blockIdx.x >> 3);
        const int bm  = wg >> 2;
        const int bn  = wg & 3;
        const int gm0 = bm * BM;
        const int gn0 = bn * BN;

        const int wm = wid & 1;     // m-half (64 rows)
        const int wn = wid >> 1;    // n-quarter (32 cols)
        const int fr = lane & 15;
        const int fq = lane >> 4;

        f32x4 acc[4][2] = {};

        for (int k0 = 0; k0 < DE_; k0 += BK) {
            #pragma unroll
            for (int s = 0; s < 4; ++s) {       // stage A (f32 -> bf16)
                const int id  = s * 256 + t;
                const int row = id >> 3;
                const int k8  = id & 7;
                const float4 a0 = *(const float4*)(sent + (size_t)(gm0 + row) * DE_ + k0 + k8 * 8);
                const float4 a1 = *(const float4*)(sent + (size_t)(gm0 + row) * DE_ + k0 + k8 * 8 + 4);
                short8 v;
                v[0] = f2bf(a0.x); v[1] = f2bf(a0.y); v[2] = f2bf(a0.z); v[3] = f2bf(a0.w);
                v[4] = f2bf(a1.x); v[5] = f2bf(a1.y); v[6] = f2bf(a1.z); v[7] = f2bf(a1.w);
                const int widx = (row * BK + k8 * 8) ^ ((row & 7) << 3);
                *(short8*)(As + widx) = v;
            }
            #pragma unroll
            for (int s = 0; s < 2; ++s) {       // stage B (bf16 passthrough)
                const int id = s * 256 + t;
                const int n  = id >> 3;
                const int k8 = id & 7;
                short8 v = *(const short8*)(wT + (size_t)(gn0 + n) * DE_ + k0 + k8 * 8);
                const int widx = (n * BK + k8 * 8) ^ ((n & 7) << 3);
                *(short8*)(Bs + widx) = v;
            }
            __syncthreads();

            #pragma unroll
            for (int ks = 0; ks < 2; ++ks) {
                short8 af[4], bfr[2];
                #pragma unroll
                for (int mf = 0; mf < 4; ++mf) {
                    const int row = wm * 64 + mf * 16 + fr;
                    af[mf] = *(const short8*)(As + ((row * BK + ks * 32 + fq * 8) ^ ((row & 7) << 3)));
                }
                #pragma unroll
                for (int nf = 0; nf < 2; ++nf) {
                    const int n = wn * 32 + nf * 16 + fr;
                    bfr[nf] = *(const short8*)(Bs + ((n * BK + ks * 32 + fq * 8) ^ ((n & 7) << 3)));
                }
                #pragma unroll
                for (int mf = 0; mf < 4; ++mf)
                    #pragma unroll
                    for (int nf = 0; nf < 2; ++nf)
                        acc[mf][nf] = __builtin_amdgcn_mfma_f32_16x16x32_bf16(
                            af[mf], bfr[nf], acc[mf][nf], 0, 0, 0);
            }
            __syncthreads();
        }

        // epilogue: C/D layout col=lane&15, row=(lane>>4)*4+r; store bf16
        #pragma unroll
        for (int nf = 0; nf < 2; ++nf) {
            const int col = gn0 + wn * 32 + nf * 16 + fr;
            const float bval = bsh[col];
            #pragma unroll
            for (int mf = 0; mf < 4; ++mf) {
                #pragma unroll
                for (int r = 0; r < 4; ++r) {
                    const int row = gm0 + wm * 64 + mf * 16 + fq * 4 + r;
                    Pb[(size_t)row * D_ + col] = f2bf(acc[mf][nf][r] + bval);
                }
            }
        }
    } else {
        // ---------------- t==0 / t==1 rows ----------------
        const int bid2 = blockIdx.x - NGEMM;
        const int r0w  = bid2 * 128 + wid * 32;

        #pragma unroll
        for (int b4 = 0; b4 < 4; ++b4) {
            const int r0 = r0w + b4 * 8;
            const float* src[8];
            int tt8[8];
            #pragma unroll
            for (int i = 0; i < 8; ++i) {
                const int row = r0 + i;
                const int tt  = item_type[row];
                tt8[i] = tt;
                const int a = arg_idx[row];
                int np = a - NSIL_;
                np = np < 0 ? 0 : (np > A_ - 1 ? A_ - 1 : np);
                const float* s0 = op_emb + (size_t)op_tokens[row] * D_;
                const float* s1 = (a < NSIL_)
                                  ? silent + (size_t)a * D_
                                  : nodes + (size_t)avail[(size_t)row * A_ + np] * D_;
                src[i] = (tt == 0) ? s0 : s1;   // t==2: harmless dummy read
            }
            float4 v[8];
            #pragma unroll
            for (int i = 0; i < 8; ++i)
                v[i] = *(const float4*)(src[i] + lane * 4);
            #pragma unroll
            for (int i = 0; i < 8; ++i)
                if (tt8[i] != 2)
                    *(float4*)(out + (size_t)(r0 + i) * D_ + lane * 4) = v[i];
        }
    }
}

// ---------------------------------------------------------------------------
// t==2 rows only: gather bf16 P row, expand to f32, write out.
// 512 blocks x 4 waves x 16 rows.
// ---------------------------------------------------------------------------
__global__ __launch_bounds__(256) void srse_t2(
    const unsigned short* __restrict__ Pb,        // (MS_, D_) bf16
    const int*            __restrict__ shift_idx, // (B*L)
    const int*            __restrict__ item_type, // (B*L)
    float*                __restrict__ out)       // (B*L, D_)
{
    const int wid  = threadIdx.x >> 6;
    const int lane = threadIdx.x & 63;
    const int r0   = blockIdx.x * 64 + wid * 16;

    int tt[16], ss[16];
    #pragma unroll
    for (int i = 0; i < 16; ++i) tt[i] = item_type[r0 + i];
    #pragma unroll
    for (int i = 0; i < 16; ++i) ss[i] = shift_idx[r0 + i];

    #pragma unroll
    for (int i = 0; i < 16; ++i) {
        if (tt[i] == 2) {                          // wave-uniform per row
            const int row = r0 + i;
            const int b   = row >> 11;             // row / L_
            const unsigned short* p = Pb + (size_t)((b << 10) + ss[i]) * D_;
            const short4 x = *(const short4*)(p + lane * 4);   // 8B/lane
            float4 o;
            o.x = bf2f((unsigned short)x.x);
            o.y = bf2f((unsigned short)x.y);
            o.z = bf2f((unsigned short)x.z);
            o.w = bf2f((unsigned short)x.w);
            *(float4*)(out + (size_t)row * D_ + lane * 4) = o;
        }
    }
}

// ---------------------------------------------------------------------------
extern "C" void kernel_launch(void* const* d_in, const int* in_sizes, int n_in,
                              void* d_out, int out_size, void* d_ws, size_t ws_size,
                              hipStream_t stream) {
    const float* sent      = (const float*)d_in[0];
    const float* nodes     = (const float*)d_in[1];
    const float* silent    = (const float*)d_in[2];
    const float* op_emb    = (const float*)d_in[3];
    const float* w         = (const float*)d_in[4];
    const float* bsh       = (const float*)d_in[5];
    const int*   op_tokens = (const int*)d_in[6];
    const int*   arg_idx   = (const int*)d_in[7];
    const int*   shift_idx = (const int*)d_in[8];
    const int*   item_type = (const int*)d_in[9];
    const int*   avail     = (const int*)d_in[10];
    float*       out       = (float*)d_out;

    unsigned short* wT = (unsigned short*)d_ws;                       // 256 KB
    unsigned short* Pb = (unsigned short*)((char*)d_ws + D_ * DE_ * 2); // 8 MB

    srse_wt<<<DE_, 256, 0, stream>>>(w, wT);

    srse_gemm_t01<<<NGEMM + NT01, 256, 0, stream>>>(
        sent, wT, bsh, Pb, op_emb, silent, nodes,
        op_tokens, arg_idx, item_type, avail, out);

    srse_t2<<<(B_ * L_) / 64, 256, 0, stream>>>(Pb, shift_idx, item_type, out);
}